// Round 1
// 201.125 us; speedup vs baseline: 1.0671x; 1.0671x over previous
//
#include <hip/hip_runtime.h>

#define IN_C  128
#define OUT_C 256
#define HIMG  56
#define WIMG  56
#define BIMG  32
#define HW    (HIMG * WIMG)     // 3136
#define KW    1152              // 9*128

#define BM    128               // oc per block
#define TH    4                 // output rows per block
#define XROWS 6                 // TH + 2 halo
#define XCOLS 58                // 56 + 2 halo (padded NHWC width)
#define NPIXT (XROWS * XCOLS)   // 348 staged pixels
#define XS_SH (NPIXT * 32)      // 11136 shorts = 22272 B per X buffer
#define AS_SH 4096              // shorts per A buffer (8192 B = 128 oc x 32 k bf16)
#define NT    36                // taps * icq
#define WT_TILES 39             // 36 real + 3 pad (stage-ahead 3)
#define XCH   (NPIXT * 4)       // 1392 16-B chunks per X buffer

#define NX_BYTES 27557888u      // 32*58*58*128*2 padded NHWC bf16

typedef __attribute__((ext_vector_type(8))) short short8;
typedef __attribute__((ext_vector_type(4))) float float4_;

__device__ __forceinline__ unsigned short f32_to_bf16_rne(float f) {
    unsigned u = __builtin_bit_cast(unsigned, f);
    u += 0x7FFFu + ((u >> 16) & 1u);
    return (unsigned short)(u >> 16);
}

// async 16B global->LDS (DMA; lands at lds_base + lane*16, counted by vmcnt)
#define ASYNC16(g, l) __builtin_amdgcn_global_load_lds( \
    (const __attribute__((address_space(1))) unsigned int*)(g), \
    (__attribute__((address_space(3))) unsigned int*)(l), 16, 0, 0)

// ---------------------------------------------------------------------------
// Pre-pass 1: x (NCHW fp32) -> zero-padded NHWC bf16 [b][hp 0..57][wp 0..57][c]
// Borders (hp/wp == 0 or 57) are zeros -> conv kernel has no validity masks.
// ---------------------------------------------------------------------------
__global__ __launch_bounds__(256) void x_to_nhwc(
    const float* __restrict__ x, unsigned short* __restrict__ nx)
{
    __shared__ unsigned short T[128][58];   // [c][w], pitch 58 (odd dwords -> spread)
    const int b  = blockIdx.x;
    const int hp = blockIdx.y;              // 0..57
    unsigned short* dst = nx + (size_t)(b * 58 + hp) * 58 * 128;

    if (hp == 0 || hp == 57) {
        for (int i = threadIdx.x; i < 58 * 128; i += 256) dst[i] = 0;
        return;
    }
    const int h = hp - 1;
    // read 128c x 56w coalesced along w, convert, store transposed
    for (int e = threadIdx.x; e < 128 * 56; e += 256) {
        int c = e / 56, w = e - c * 56;
        T[c][w] = f32_to_bf16_rne(x[(size_t)(b * IN_C + c) * HW + h * WIMG + w]);
    }
    __syncthreads();
    // write 58 wp x 128c, coalesced along c; wp borders are zeros
    for (int e = threadIdx.x; e < 58 * 128; e += 256) {
        int wp = e >> 7, c = e & 127;
        dst[wp * 128 + c] = (wp == 0 || wp == 57) ? (unsigned short)0 : T[c][wp - 1];
    }
}

// ---------------------------------------------------------------------------
// Pre-pass 2: weights -> [half][tile t=icq*9+r][oc 128][chunk 4][elem 8] bf16,
// with the per-row XOR chunk swizzle BAKED IN (chunk c holds data slot
// c ^ ((oc>>1)&3)), so conv can stage linearly via global_load_lds and read
// with the same XOR -> <=2-way LDS banks. Tiles 36..38 are zero padding.
// ---------------------------------------------------------------------------
__global__ void repack_w(const float* __restrict__ Wk, unsigned short* __restrict__ Wt) {
    int idx = blockIdx.x * 256 + threadIdx.x;
    if (idx >= 2 * WT_TILES * 4096) return;
    int half = idx / (WT_TILES * 4096);
    int rem  = idx - half * (WT_TILES * 4096);
    int t    = rem >> 12;
    int win  = rem & 4095;
    int oc   = win >> 5;
    int c    = (win >> 3) & 3;
    int j    = win & 7;
    unsigned short v = 0;
    if (t < NT) {
        int icq = t / 9, r = t - icq * 9;
        int s  = c ^ ((oc >> 1) & 3);
        int ic = icq * 32 + s * 8 + j;
        v = f32_to_bf16_rne(Wk[(size_t)(half * 128 + oc) * KW + ic * 9 + r]);
    }
    Wt[idx] = v;
}

// ---------------------------------------------------------------------------
// Implicit-GEMM conv, fully DMA-staged and software-pipelined:
//   - A (weights) quad-buffered, staged 3 taps ahead via global_load_lds
//   - X (activations) double-buffered per icq, staged 9 taps ahead
//   - one raw s_barrier per tap, counted vmcnt (never 0) keeps loads in flight
// ---------------------------------------------------------------------------
__global__ __launch_bounds__(256, 2) void conv_gemm(
    const unsigned short* __restrict__ nx,   // padded NHWC bf16
    const unsigned short* __restrict__ Wt,   // repacked weights
    const float* __restrict__ bias, float* __restrict__ out)
{
    __shared__ __align__(16) unsigned short As[4 * AS_SH];   // 32768 B
    __shared__ __align__(16) unsigned short Xs[2 * XS_SH];   // 44544 B

    const int tid  = threadIdx.x;
    const int lane = tid & 63;
    const int wid  = tid >> 6;
    const int bx   = blockIdx.x;            // 0..447
    const int b    = bx / 14;
    const int h0   = (bx - b * 14) * TH;
    const int half = blockIdx.y;

    // 4 waves, each owns a 64(m) x 112(n) quadrant: 4x7 MFMA tiles
    const int wm = (wid >> 1) * 64;
    const int wn = (wid & 1) * 112;
    const int q  = lane >> 4;

    int lp0[7], outoff[7];
    #pragma unroll
    for (int ni = 0; ni < 7; ++ni) {
        int nl  = wn + ni * 16 + (lane & 15);
        int ht_ = nl / 56;
        int wt_ = nl - ht_ * 56;
        lp0[ni]    = (ht_ + 1) * XCOLS + (wt_ + 1);  // tap (0,0) pixel in Xs
        outoff[ni] = (h0 + ht_) * WIMG + wt_;
    }

    // A-frag read offsets (shorts), XOR swizzle matching repack layout
    int aoff[4];
    #pragma unroll
    for (int mi = 0; mi < 4; ++mi) {
        int row = wm + mi * 16 + (lane & 15);
        aoff[mi] = row * 32 + ((q ^ ((row >> 1) & 3)) * 8);
    }

    // X staging: per-wave 348 chunks (5 full wave-instrs + 28-lane tail).
    // Source chunk pre-swizzled (rule #21: linear LDS dest + swizzled source).
    int xgo[6];
    #pragma unroll
    for (int i = 0; i < 6; ++i) {
        int C = wid * 348 + i * 64 + lane;
        if (C >= XCH) C = XCH - 1;          // masked lanes only; keep addr sane
        int p = C >> 2, c = C & 3;
        int row  = p / XCOLS;
        int colw = p - row * XCOLS;
        int s = c ^ ((p >> 1) & 3);
        xgo[i] = ((b * 58 + h0 + row) * 58 + colw) * 256 + s * 16;
    }
    const char* nxc = (const char*)nx;
    const char* wtc = (const char*)Wt + (size_t)half * WT_TILES * 8192
                    + (wid * 2) * 1024 + lane * 16;

    float4_ acc[4][7];
    #pragma unroll
    for (int mi = 0; mi < 4; ++mi)
        #pragma unroll
        for (int ni = 0; ni < 7; ++ni) acc[mi][ni] = (float4_)0.0f;

    auto stage_x = [&](int icq1, int bufX1) {
        #pragma unroll
        for (int i = 0; i < 5; ++i)
            ASYNC16(nxc + xgo[i] + icq1 * 64,
                    &Xs[bufX1 * XS_SH + (wid * 348 + i * 64) * 8]);
        if (lane < 28)
            ASYNC16(nxc + xgo[5] + icq1 * 64,
                    &Xs[bufX1 * XS_SH + (wid * 348 + 5 * 64) * 8]);
    };
    auto stage_a = [&](int tile) {
        const char* src = wtc + (size_t)tile * 8192;
        unsigned short* dst = &As[(tile & 3) * AS_SH + (wid * 2) * 512];
        ASYNC16(src, dst);
        ASYNC16(src + 1024, dst + 512);
    };

    // prologue: X(0) first (so A-waits imply X done), then A(0..2)
    stage_x(0, 0);
    stage_a(0); stage_a(1); stage_a(2);

    for (int t = 0; t < NT; ++t) {
        const int icq = t / 9;
        const int r   = t - icq * 9;

        // counted waits: A(t) issued 3 steps back. Newer in-flight loads:
        //   r in {1,2,3}: X-batch(6) + 2 A-batches(4) = 10 ; else 2 A-batches = 4
        if (r >= 1 && r <= 3) asm volatile("s_waitcnt vmcnt(10)" ::: "memory");
        else                  asm volatile("s_waitcnt vmcnt(4)"  ::: "memory");
        __builtin_amdgcn_s_barrier();
        asm volatile("" ::: "memory");      // fence: no LDS reads above barrier

        const unsigned short* Ab = &As[(t & 3) * AS_SH];
        const unsigned short* Xb = &Xs[(icq & 1) * XS_SH];
        const int doff = (r / 3 - 1) * XCOLS + (r - (r / 3) * 3 - 1);

        short8 afr[4], bfr[7];
        #pragma unroll
        for (int mi = 0; mi < 4; ++mi) afr[mi] = *(const short8*)&Ab[aoff[mi]];
        #pragma unroll
        for (int ni = 0; ni < 7; ++ni) {
            int lp   = lp0[ni] + doff;
            int slot = q ^ ((lp >> 1) & 3);
            bfr[ni]  = *(const short8*)&Xb[lp * 32 + slot * 8];
        }

        // prefetch: A 3 taps ahead (Wt zero-padded to 39 tiles),
        // X one icq ahead (icq=4 reads in-bounds garbage, never used)
        stage_a(t + 3);
        if (r == 0) stage_x(icq + 1, (icq + 1) & 1);

        __builtin_amdgcn_s_setprio(1);
        #pragma unroll
        for (int mi = 0; mi < 4; ++mi)
            #pragma unroll
            for (int ni = 0; ni < 7; ++ni)
                acc[mi][ni] = __builtin_amdgcn_mfma_f32_16x16x32_bf16(
                    afr[mi], bfr[ni], acc[mi][ni], 0, 0, 0);
        __builtin_amdgcn_s_setprio(0);
    }

    // epilogue: C/D layout col=lane&15, row=(lane>>4)*4+v (m89-verified)
    const int rowg = (lane >> 4) * 4;
    const int oc0  = half * BM;
    #pragma unroll
    for (int mi = 0; mi < 4; ++mi) {
        #pragma unroll
        for (int v = 0; v < 4; ++v) {
            const int oc = oc0 + wm + mi * 16 + rowg + v;
            const float bv = bias[oc];
            float* obase = out + (size_t)(b * OUT_C + oc) * HW;
            #pragma unroll
            for (int ni = 0; ni < 7; ++ni)
                obase[outoff[ni]] = acc[mi][ni][v] + bv;
        }
    }
}

extern "C" void kernel_launch(void* const* d_in, const int* in_sizes, int n_in,
                              void* d_out, int out_size, void* d_ws, size_t ws_size,
                              hipStream_t stream) {
    (void)in_sizes; (void)n_in; (void)out_size; (void)ws_size;
    const float* x    = (const float*)d_in[0];
    const float* Wk   = (const float*)d_in[1];
    const float* bias = (const float*)d_in[2];
    float* out        = (float*)d_out;

    // workspace: [0, 27557888) padded NHWC bf16 ; then 638976 B repacked W
    unsigned short* nx = (unsigned short*)d_ws;
    unsigned short* Wt = (unsigned short*)((char*)d_ws + NX_BYTES);

    x_to_nhwc<<<dim3(BIMG, 58), dim3(256), 0, stream>>>(x, nx);
    repack_w<<<dim3((2 * WT_TILES * 4096 + 255) / 256), dim3(256), 0, stream>>>(Wk, Wt);
    conv_gemm<<<dim3(BIMG * (HIMG / TH), OUT_C / BM), dim3(256), 0, stream>>>(nx, Wt, bias, out);
}